// Round 15
// baseline (93.938 us; speedup 1.0000x reference)
//
#include <hip/hip_runtime.h>

// spec (32, 4000, 161, 2) f32.
//   pow[b,t,k]  = re^2 + im^2
//   g0[b,t]     = sqrt((2*sum(pow[1..159]) + pow[0] + pow[160]) / 320)
//   gain[b,t]   = EMA over t: c = 0.9c + 0.1*g0  (gain[b,0]=g0[b,0])
//   new_spec    = spec / (gain + 0.001)
// Outputs flat-concat: new_spec (41,216,000 f32) then gain (128,000 f32).
//
// R11 split + K3 REVERSED block walk: after K1's full spec read, the L3
// (memory-side, survives dispatch boundary) holds the MRU tail of spec
// (high addresses). K3 reads high->low so those lines are consumed before
// its own write stream evicts them (330 MB working set > 256 MB L3).

typedef float f32x4 __attribute__((ext_vector_type(4)));
typedef float f32x2 __attribute__((ext_vector_type(2)));

#define B_SZ 32
#define T_SZ 4000
#define FRAME_F 322              // floats per frame (161 bins * 2)
#define FRAMES (B_SZ * T_SZ)     // 128000
#define N_SPEC ((size_t)FRAMES * FRAME_F)  // 41,216,000
#define N4 (N_SPEC / 4)          // 10,304,000 f32x4 (exact)
#define NBLK3 (N4 / 256)         // 40250 (exact, no tail)
#define EMA_W 384                // 0.9^384 ~ 4e-18: below f32 resolution
#define HALO (EMA_W - 1)         // 383
#define BLOCK 256
#define NGROUPS (FRAMES / 2)     // 64000 8-lane groups (2 frames each)

// ---- K1: per-frame gain g0; 2 frames per 8-lane group, whole-line loads ----
__global__ __launch_bounds__(BLOCK) void k_frame_gain(
    const float* __restrict__ spec, float* __restrict__ g0) {
  int grp = (blockIdx.x * BLOCK + threadIdx.x) >> 3;   // group id
  int sub = threadIdx.x & 7;                           // lane in group
  if (grp >= NGROUPS) return;

  const float* base = spec + (size_t)grp * 644;        // 2 frames = 644 floats
  float accA = 0.f, accB = 0.f;
  float pw0A = 0.f, pw160A = 0.f, pw0B = 0.f, pw160B = 0.f;

#pragma unroll
  for (int k = 0; k < 21; ++k) {
    int idx = k * 8 + sub;                             // f32x4 idx in [0,161)
    if (idx < 161) {
      f32x4 v = *(const f32x4*)(base + idx * 4);
      float s01 = v.x * v.x + v.y * v.y;
      float s23 = v.z * v.z + v.w * v.w;
      if (idx < 80) {
        accA += s01 + s23;
        if (idx == 0) pw0A = s01;                      // floats 0,1   (sub==0)
      } else if (idx == 80) {                          // straddle (sub==0)
        accA += s01; accB += s23;
        pw160A = s01;                                  // floats 320,321
        pw0B   = s23;                                  // floats 322,323
      } else {
        accB += s01 + s23;
        if (idx == 160) pw160B = s23;                  // floats 642,643 (sub==0)
      }
    }
  }
#pragma unroll
  for (int off = 1; off < 8; off <<= 1) {
    accA += __shfl_xor(accA, off, 64);
    accB += __shfl_xor(accB, off, 64);
  }
  if (sub == 0) {                                      // endpoint pows live here
    f32x2 g;
    g.x = sqrtf((2.f * accA - pw0A - pw160A) * (1.0f / 320.0f));
    g.y = sqrtf((2.f * accB - pw0B - pw160B) * (1.0f / 320.0f));
    *(f32x2*)(g0 + 2 * grp) = g;
  }
}

// ---- K2: EMA via truncated window (exact for t < EMA_W); emits gain+inv ----
__global__ __launch_bounds__(BLOCK) void k_ema(
    const float* __restrict__ g0, float* __restrict__ gain_out,
    float* __restrict__ inv_out) {
  __shared__ float xs[HALO + 1 + 256];
  int b  = blockIdx.y;
  int t0 = blockIdx.x * 256;
  int lo = t0 - HALO; if (lo < 0) lo = 0;
  int hi = t0 + 256; if (hi > T_SZ) hi = T_SZ;     // exclusive
  int n  = hi - lo;
  const float* gb = g0 + b * T_SZ;

  for (int i = threadIdx.x; i < n; i += BLOCK) xs[i] = gb[lo + i];
  __syncthreads();

  int t = t0 + (int)threadIdx.x;
  if (t >= T_SZ) return;
  int s = t - HALO; if (s < 1) s = 1;
  float c = (s == 1) ? xs[0] : 0.f;                // lo==0 whenever s==1
  for (int k = s; k <= t; ++k) c = c * 0.9f + xs[k - lo] * 0.1f;
  gain_out[b * T_SZ + t] = c;
  inv_out[b * T_SZ + t]  = 1.0f / (c + 0.001f);
}

// ---- K3: out = spec * inv[frame]; flat f32x4, REVERSED block order ----
__global__ __launch_bounds__(BLOCK) void k_apply(
    const float* __restrict__ spec, const float* __restrict__ inv_g,
    float* __restrict__ out) {
  // Reverse the block walk: earliest-dispatched blocks consume the
  // L3-MRU (high-address) spec lines left by K1 before writes evict them.
  size_t i = (size_t)(NBLK3 - 1 - blockIdx.x) * BLOCK + threadIdx.x;
  f32x4 v = ((const f32x4*)spec)[i];
  unsigned p0 = (unsigned)(2 * i);                 // pair idx of (v.x,v.y)
  unsigned f0 = p0 / 161u;                         // frame (magic mul)
  unsigned r  = p0 - f0 * 161u;
  unsigned f1 = f0 + (r == 160u);                  // frame of second pair
  float i0 = inv_g[f0];
  float i1 = inv_g[f1];
  f32x4 rr;
  rr.x = v.x * i0; rr.y = v.y * i0;
  rr.z = v.z * i1; rr.w = v.w * i1;
  // nt store: don't evict spec from caches with the write stream
  __builtin_nontemporal_store(rr, (f32x4*)out + i);
}

extern "C" void kernel_launch(void* const* d_in, const int* in_sizes, int n_in,
                              void* d_out, int out_size, void* d_ws, size_t ws_size,
                              hipStream_t stream) {
  const float* spec = (const float*)d_in[0];
  float* out   = (float*)d_out;
  float* gain  = out + N_SPEC;       // gain output lives in the d_out tail
  float* g0    = (float*)d_ws;       // 128000 f32
  float* inv_g = g0 + FRAMES;        // 128000 f32

  // K1: 32 groups (64 frames) per block -> 2000 blocks
  k_frame_gain<<<NGROUPS * 8 / BLOCK, BLOCK, 0, stream>>>(spec, g0);

  // K2: (16, 32) grid
  dim3 g2((T_SZ + 255) / 256, B_SZ);
  k_ema<<<g2, BLOCK, 0, stream>>>(g0, gain, inv_g);

  // K3: flat one-shot, reversed walk, 40250 blocks (exact)
  k_apply<<<NBLK3, BLOCK, 0, stream>>>(spec, inv_g, out);
}

// Round 16
// 92.799 us; speedup vs baseline: 1.0123x; 1.0123x over previous
//
#include <hip/hip_runtime.h>

// spec (32, 4000, 161, 2) f32.
//   pow[b,t,k]  = re^2 + im^2
//   g0[b,t]     = sqrt((2*sum(pow[1..159]) + pow[0] + pow[160]) / 320)
//   gain[b,t]   = EMA over t: c = 0.9c + 0.1*g0  (gain[b,0]=g0[b,0])
//   new_spec    = spec / (gain + 0.001)
// Outputs flat-concat: new_spec (41,216,000 f32) then gain (128,000 f32).
//
// FINAL (R11, best measured 92.8us): 3-kernel split at the practical
// memory roofline: 495 MB compulsory HBM @ ~5.3-5.8 TB/s mixed-stream.
//  K1: g0; 2 frames per 8-lane group -> every 64B line consumed exactly
//      once by one instruction, 21 indep loads/lane, 3-shfl reduce (~25us).
//  K2: truncated-window EMA (0.9^384 < f32 eps -> bit-accurate vs scan for
//      this data), emits gain and inv=1/(gain+1e-3) (~3us).
//  K3: flat f32x4 stream out = spec*inv, nt stores (~57us).

typedef float f32x4 __attribute__((ext_vector_type(4)));
typedef float f32x2 __attribute__((ext_vector_type(2)));

#define B_SZ 32
#define T_SZ 4000
#define FRAME_F 322              // floats per frame (161 bins * 2)
#define FRAMES (B_SZ * T_SZ)     // 128000
#define N_SPEC ((size_t)FRAMES * FRAME_F)  // 41,216,000
#define N4 (N_SPEC / 4)          // 10,304,000 f32x4 (exact)
#define EMA_W 384                // 0.9^384 ~ 4e-18: below f32 resolution
#define HALO (EMA_W - 1)         // 383
#define BLOCK 256
#define NGROUPS (FRAMES / 2)     // 64000 8-lane groups (2 frames each)

// ---- K1: per-frame gain g0; 2 frames per 8-lane group, whole-line loads ----
__global__ __launch_bounds__(BLOCK) void k_frame_gain(
    const float* __restrict__ spec, float* __restrict__ g0) {
  int grp = (blockIdx.x * BLOCK + threadIdx.x) >> 3;   // group id
  int sub = threadIdx.x & 7;                           // lane in group
  if (grp >= NGROUPS) return;

  const float* base = spec + (size_t)grp * 644;        // 2 frames = 644 floats
  float accA = 0.f, accB = 0.f;
  float pw0A = 0.f, pw160A = 0.f, pw0B = 0.f, pw160B = 0.f;

#pragma unroll
  for (int k = 0; k < 21; ++k) {
    int idx = k * 8 + sub;                             // f32x4 idx in [0,161)
    if (idx < 161) {
      f32x4 v = *(const f32x4*)(base + idx * 4);
      float s01 = v.x * v.x + v.y * v.y;
      float s23 = v.z * v.z + v.w * v.w;
      if (idx < 80) {
        accA += s01 + s23;
        if (idx == 0) pw0A = s01;                      // floats 0,1   (sub==0)
      } else if (idx == 80) {                          // straddle (sub==0)
        accA += s01; accB += s23;
        pw160A = s01;                                  // floats 320,321
        pw0B   = s23;                                  // floats 322,323
      } else {
        accB += s01 + s23;
        if (idx == 160) pw160B = s23;                  // floats 642,643 (sub==0)
      }
    }
  }
#pragma unroll
  for (int off = 1; off < 8; off <<= 1) {
    accA += __shfl_xor(accA, off, 64);
    accB += __shfl_xor(accB, off, 64);
  }
  if (sub == 0) {                                      // endpoint pows live here
    f32x2 g;
    g.x = sqrtf((2.f * accA - pw0A - pw160A) * (1.0f / 320.0f));
    g.y = sqrtf((2.f * accB - pw0B - pw160B) * (1.0f / 320.0f));
    *(f32x2*)(g0 + 2 * grp) = g;
  }
}

// ---- K2: EMA via truncated window (exact for t < EMA_W); emits gain+inv ----
__global__ __launch_bounds__(BLOCK) void k_ema(
    const float* __restrict__ g0, float* __restrict__ gain_out,
    float* __restrict__ inv_out) {
  __shared__ float xs[HALO + 1 + 256];
  int b  = blockIdx.y;
  int t0 = blockIdx.x * 256;
  int lo = t0 - HALO; if (lo < 0) lo = 0;
  int hi = t0 + 256; if (hi > T_SZ) hi = T_SZ;     // exclusive
  int n  = hi - lo;
  const float* gb = g0 + b * T_SZ;

  for (int i = threadIdx.x; i < n; i += BLOCK) xs[i] = gb[lo + i];
  __syncthreads();

  int t = t0 + (int)threadIdx.x;
  if (t >= T_SZ) return;
  int s = t - HALO; if (s < 1) s = 1;
  float c = (s == 1) ? xs[0] : 0.f;                // lo==0 whenever s==1
  for (int k = s; k <= t; ++k) c = c * 0.9f + xs[k - lo] * 0.1f;
  gain_out[b * T_SZ + t] = c;
  inv_out[b * T_SZ + t]  = 1.0f / (c + 0.001f);
}

// ---- K3: out = spec * inv[frame]; flat one-shot f32x4, nt stores ----
__global__ __launch_bounds__(BLOCK) void k_apply(
    const float* __restrict__ spec, const float* __restrict__ inv_g,
    float* __restrict__ out) {
  size_t i = (size_t)blockIdx.x * BLOCK + threadIdx.x;   // f32x4 index
  if (i >= N4) return;
  f32x4 v = ((const f32x4*)spec)[i];
  unsigned p0 = (unsigned)(2 * i);                 // pair idx of (v.x,v.y)
  unsigned f0 = p0 / 161u;                         // frame (magic mul)
  unsigned r  = p0 - f0 * 161u;
  unsigned f1 = f0 + (r == 160u);                  // frame of second pair
  float i0 = inv_g[f0];
  float i1 = inv_g[f1];
  f32x4 rr;
  rr.x = v.x * i0; rr.y = v.y * i0;
  rr.z = v.z * i1; rr.w = v.w * i1;
  // nt store: don't evict spec from caches with the write stream
  __builtin_nontemporal_store(rr, (f32x4*)out + i);
}

extern "C" void kernel_launch(void* const* d_in, const int* in_sizes, int n_in,
                              void* d_out, int out_size, void* d_ws, size_t ws_size,
                              hipStream_t stream) {
  const float* spec = (const float*)d_in[0];
  float* out   = (float*)d_out;
  float* gain  = out + N_SPEC;       // gain output lives in the d_out tail
  float* g0    = (float*)d_ws;       // 128000 f32
  float* inv_g = g0 + FRAMES;        // 128000 f32

  // K1: 32 groups (64 frames) per block -> 2000 blocks
  k_frame_gain<<<NGROUPS * 8 / BLOCK, BLOCK, 0, stream>>>(spec, g0);

  // K2: (16, 32) grid
  dim3 g2((T_SZ + 255) / 256, B_SZ);
  k_ema<<<g2, BLOCK, 0, stream>>>(g0, gain, inv_g);

  // K3: flat one-shot, 40250 blocks
  k_apply<<<(int)((N4 + BLOCK - 1) / BLOCK), BLOCK, 0, stream>>>(spec, inv_g, out);
}